// Round 10
// baseline (427.530 us; speedup 1.0000x reference)
//
#include <hip/hip_runtime.h>
#include <hip/hip_bf16.h>
#include <math.h>
#include <stdint.h>

#define D 128

typedef unsigned short u16;
typedef unsigned int u32;
typedef __attribute__((ext_vector_type(8))) short bf16x8;
typedef __attribute__((ext_vector_type(4))) float f32x4;
typedef __attribute__((ext_vector_type(4))) unsigned short u16x4;

// ws layout in u16 units:
#define FRAG_WE1 0
#define FRAG_WE2 32768
#define FRAG_WC1 49152
#define FRAG_WN1 65536
#define FRAG_WN2 98304
#define WE1R_OFF 114688   // float[128] = 256 u16
#define AGG_OFF  131072   // bf16 agg[N*D] (BA path)
// bf16 h table (HB path) at AGG_OFF + N*D
// sort arrays (SORT path) after hb: u32 deg[N], u32 cur[N], uint2 rc[E]

__device__ __forceinline__ float silu_f(float x) {
    // x * rcp(1+exp(-x)) — bf16 output tolerates 1-ulp rcp
    return x * __builtin_amdgcn_rcpf(1.0f + __expf(-x));
}
__device__ __forceinline__ u16 f2bf(float x) {
    union { float f; unsigned int u; } v; v.f = x;
    unsigned int r = v.u + 0x7fffu + ((v.u >> 16) & 1u);
    return (u16)(r >> 16);
}
__device__ __forceinline__ float bf2f(u16 u) {
    union { unsigned int u; float f; } v; v.u = ((unsigned int)u) << 16; return v.f;
}
__device__ __forceinline__ unsigned pk2bf(float a, float b) {
    union { __hip_bfloat162 v; unsigned u; } u;
    u.v = __float22bfloat162_rn(make_float2(a, b));
    return u.u;
}
// packed bf16 atomic add — raw asm (clang builtin removed on ROCm 7)
__device__ __forceinline__ void pk_agg_add(u16* addr, unsigned packed) {
    asm volatile("global_atomic_pk_add_bf16 %0, %1, off"
                 :: "v"(addr), "v"(packed) : "memory");
}

// ---------------- prep: weights -> fragment-ordered bf16 (fallback tiers) ----------------
// B-frag: elem(nt,kk,lane,j) = W[k*128+n], k = kk*32+(lane>>4)*8+j, n = nt*16+(lane&15)
__global__ __launch_bounds__(256) void egnn_prep(
    const float* __restrict__ We1, const float* __restrict__ We2,
    const float* __restrict__ Wc1, const float* __restrict__ Wn1,
    const float* __restrict__ Wn2, u16* __restrict__ ws)
{
    int i = blockIdx.x * blockDim.x + threadIdx.x;   // 32768 threads
    u16* We1F = ws + FRAG_WE1;
    u16* We2F = ws + FRAG_WE2;
    u16* Wc1F = ws + FRAG_WC1;
    u16* Wn1F = ws + FRAG_WN1;
    u16* Wn2F = ws + FRAG_WN2;
    float* We1r = (float*)(ws + WE1R_OFF);

    if (i < 32768) {
        int j = i & 7, l = (i >> 3) & 63, kk = (i >> 9) & 7, nt = i >> 12;
        int k = kk * 32 + (l >> 4) * 8 + j;
        int n = nt * 16 + (l & 15);
        We1F[i] = f2bf(We1[k * D + n]);
        Wn1F[i] = f2bf(Wn1[k * D + n]);
    }
    if (i < 16384) {
        int j = i & 7, l = (i >> 3) & 63, kk = (i >> 9) & 3, nt = i >> 11;
        int k = kk * 32 + (l >> 4) * 8 + j;
        int n = nt * 16 + (l & 15);
        We2F[i] = f2bf(We2[k * D + n]);
        Wc1F[i] = f2bf(Wc1[k * D + n]);
        Wn2F[i] = f2bf(Wn2[k * D + n]);
    }
    if (i < 128) We1r[i] = We1[256 * D + i];
}

// ---------------- setup (fused): weights + zero agg + bf16 h table + pos + row count ----------------
// deg must be pre-zeroed (hipMemsetAsync) when ecount > 0.
__global__ __launch_bounds__(256) void egnn_setup(
    const float* __restrict__ h, const float* __restrict__ pos,
    const int* __restrict__ eidx,
    const float* __restrict__ We1, const float* __restrict__ We2,
    const float* __restrict__ Wc1, const float* __restrict__ Wn1,
    const float* __restrict__ Wn2,
    float* __restrict__ out, u16* __restrict__ ws,
    u32* __restrict__ deg, int ecount, int N)
{
    u16* We1F = ws + FRAG_WE1;
    u16* We2F = ws + FRAG_WE2;
    u16* Wc1F = ws + FRAG_WC1;
    u16* Wn1F = ws + FRAG_WN1;
    u16* Wn2F = ws + FRAG_WN2;
    float* We1r = (float*)(ws + WE1R_OFF);
    uint4* agg4 = (uint4*)(ws + AGG_OFF);
    uint2* hb2  = (uint2*)(ws + AGG_OFF + (size_t)N * D);

    const int nagg = N * D / 8;
    const int nh   = N * D / 4;
    const int bw   = 49280;                 // 32768 + 16384 + 128
    const int total = bw + nagg + nh + N * 3 + ecount;
    int stride = gridDim.x * blockDim.x;
    for (int i = blockIdx.x * blockDim.x + threadIdx.x; i < total; i += stride) {
        if (i < 32768) {
            int j = i & 7, l = (i >> 3) & 63, kk = (i >> 9) & 7, nt = i >> 12;
            int k = kk * 32 + (l >> 4) * 8 + j;
            int n = nt * 16 + (l & 15);
            We1F[i] = f2bf(We1[k * D + n]);
            Wn1F[i] = f2bf(Wn1[k * D + n]);
        } else if (i < 49152) {
            int i2 = i - 32768;
            int j = i2 & 7, l = (i2 >> 3) & 63, kk = (i2 >> 9) & 3, nt = i2 >> 11;
            int k = kk * 32 + (l >> 4) * 8 + j;
            int n = nt * 16 + (l & 15);
            We2F[i2] = f2bf(We2[k * D + n]);
            Wc1F[i2] = f2bf(Wc1[k * D + n]);
            Wn2F[i2] = f2bf(Wn2[k * D + n]);
        } else if (i < bw) {
            int i2 = i - 49152;
            We1r[i2] = We1[256 * D + i2];
        } else {
            int k = i - bw;
            if (k < nagg) {
                agg4[k] = make_uint4(0, 0, 0, 0);
            } else if (k < nagg + nh) {
                int j = k - nagg;
                float4 v = ((const float4*)h)[j];
                uint2 p; p.x = pk2bf(v.x, v.y); p.y = pk2bf(v.z, v.w);
                hb2[j] = p;
            } else if (k < nagg + nh + N * 3) {
                int j = k - nagg - nh;
                out[(size_t)N * D + j] = pos[j];
            } else {
                int j = k - nagg - nh - N * 3;   // fused row histogram
                atomicAdd(&deg[eidx[j]], 1u);
            }
        }
    }
}

// ---------------- init (BA): zero bf16 agg in ws, copy pos -> pos_out ----------------
__global__ __launch_bounds__(256) void egnn_init_ba(
    const float* __restrict__ pos, float* __restrict__ out,
    uint4* __restrict__ agg4, int N)
{
    int stride = gridDim.x * blockDim.x;
    int nagg = N * D / 8;
    int total = nagg + N * 3;
    for (int i = blockIdx.x * blockDim.x + threadIdx.x; i < total; i += stride) {
        if (i < nagg) agg4[i] = make_uint4(0, 0, 0, 0);
        else { int j = i - nagg; out[(size_t)N * D + j] = pos[j]; }
    }
}

// ---------------- init (fallback): zero fp32 agg (= out h region), copy pos ----------------
__global__ __launch_bounds__(256) void egnn_init_f32(
    const float* __restrict__ pos, float* __restrict__ out, int N)
{
    int stride = gridDim.x * blockDim.x;
    int hd = N * D;
    int total = hd + N * 3;
    for (int i = blockIdx.x * blockDim.x + threadIdx.x; i < total; i += stride)
        out[i] = (i < hd) ? 0.0f : pos[i - hd];
}

// ---------------- sort: single-dispatch exclusive scan ----------------
// Block b redundantly sums deg[0, b*1024) straight from L2 (<=196KB, cheap),
// then ex-scans its own 1024-chunk. Replaces scan_a+scan_b (one dispatch less).
__global__ __launch_bounds__(256) void egnn_scan(
    const u32* __restrict__ deg, u32* __restrict__ cur, int N)
{
    __shared__ u32 pred[4];
    __shared__ u32 woff[4];
    int b = blockIdx.x, t = threadIdx.x;
    int lane = t & 63;

    // prefix over [0, b*1024): strided quad sums (P is a multiple of 1024)
    u32 pre = 0;
    int P = b << 10;
    for (int i = t * 4; i < P; i += 1024) {
        uint4 v = *(const uint4*)&deg[i];
        pre += v.x + v.y + v.z + v.w;
    }
    #pragma unroll
    for (int off = 1; off < 64; off <<= 1) pre += __shfl_xor(pre, off);
    if (lane == 0) pred[t >> 6] = pre;
    __syncthreads();
    u32 blockpre = pred[0] + pred[1] + pred[2] + pred[3];

    // local chunk ex-scan (proven scan_b body)
    int i0 = P + t * 4;
    u32 d[4]; u32 s = 0;
    #pragma unroll
    for (int k = 0; k < 4; ++k) { int i = i0 + k; d[k] = (i < N) ? deg[i] : 0u; s += d[k]; }
    u32 incl = s;
    for (int off = 1; off < 64; off <<= 1) {
        u32 v = __shfl_up(incl, off);
        if (lane >= off) incl += v;
    }
    if (lane == 63) woff[t >> 6] = incl;
    __syncthreads();
    u32 ws_ = 0;
    for (int w2 = 0; w2 < (t >> 6); ++w2) ws_ += woff[w2];
    u32 ex = blockpre + ws_ + incl - s;
    #pragma unroll
    for (int k = 0; k < 4; ++k) { int i = i0 + k; if (i < N) cur[i] = ex; ex += d[k]; }
}

// ---------------- sort: scatter (row,col) pairs into row-sorted rc ----------------
__global__ __launch_bounds__(256) void egnn_scatter(
    const int* __restrict__ eidx, u32* __restrict__ cur,
    uint2* __restrict__ rc, int E)
{
    int i = blockIdx.x * blockDim.x + threadIdx.x;
    if (i < E) {
        u32 r = (u32)eidx[i];
        u32 c = (u32)eidx[E + i];
        u32 p = atomicAdd(&cur[r], 1u);
        rc[p] = make_uint2(r, c);
    }
}

// ---------------- edge kernel ----------------
// 8 waves (512 thr) per 64-edge tile; 4 blocks/CU = 100% occupancy (R9).
// One block per tile, in dispatch order — grid-stride broke sorted-window L2
// locality (R8). R10: coord path fused — Wc2 dot computed in C1's epilogue
// via m-lane shfl reduce + esum LDS; removes C1 transpose writes + coord2
// stage reads (-32KB LDS/block) and does the dot in fp32.
// SORT=1: edges arrive row-sorted via rc[]; tail does segmented fp32
// run-reduction before pk-atomics (~deg× fewer memory-side atomic ops).
template<int BA, int HB, int SORT>
__global__ __launch_bounds__(512, 8) void egnn_edge_mfma(
    const float* __restrict__ h, const u16* __restrict__ hb,
    const float* __restrict__ pos,
    const int* __restrict__ eidx, const uint2* __restrict__ rc,
    const u16* __restrict__ We1F, const float* __restrict__ We1r,
    const float* __restrict__ be1,
    const u16* __restrict__ We2F, const float* __restrict__ be2,
    const u16* __restrict__ Wc1F, const float* __restrict__ bc1,
    const float* __restrict__ Wc2,
    u16* __restrict__ aggb, float* __restrict__ aggf,
    float* __restrict__ pos_out, int E)
{
    __shared__ u16 A[64][264];
    __shared__ int erow[64], ecol[64];
    __shared__ float ediff[64][3], edist[64];
    __shared__ float es[64];        // SORT: per-edge coord scale cw/dist
    __shared__ float esum[8][64];   // per-wave partial Wc2 dots

    const int tid = threadIdx.x;
    const int w = tid >> 6, l = tid & 63;    // 8 waves
    const int q = l >> 4, m = l & 15;
    const int e0 = blockIdx.x * 64;

    if (tid < 64) {
        int e = e0 + tid;
        int r = 0, c = 0;
        if (e < E) {
            if (SORT) { uint2 p = rc[e]; r = (int)p.x; c = (int)p.y; }
            else { r = eidx[e]; c = eidx[E + e]; }
        }
        erow[tid] = r; ecol[tid] = c;
        float dx = pos[r*3+0] - pos[c*3+0];
        float dy = pos[r*3+1] - pos[c*3+1];
        float dz = pos[r*3+2] - pos[c*3+2];
        float dd = fmaxf(sqrtf(dx*dx + dy*dy + dz*dz), 1e-6f);
        ediff[tid][0] = dx; ediff[tid][1] = dy; ediff[tid][2] = dz;
        edist[tid] = dd;
    }
    __syncthreads();

    // hoist layer-1 B-frags (single 16-col tile per wave -> 8 frags, reg-resident)
    bf16x8 B1[8];
    #pragma unroll
    for (int kk = 0; kk < 8; ++kk)
        B1[kk] = *(const bf16x8*)&We1F[((w*8 + kk)*64 + l)*8];
    float b1_ = be1[w*16 + m];
    float wr1 = We1r[w*16 + m];

    // gather h[row] | h[col] -> bf16 LDS
    if (HB) {
        // 2048 16B-chunks per tile, 512 threads -> 4 iters
        #pragma unroll
        for (int p = 0; p < 4; ++p) {
            int c = p * 512 + tid;
            int el = c >> 5;
            int half = (c >> 4) & 1;
            int f0 = (c & 15) * 8;              // u16 units, 16B per chunk
            int node = half ? ecol[el] : erow[el];
            uint4 v = *(const uint4*)(hb + (size_t)node * D + f0);
            *(uint4*)&A[el][half * 128 + f0] = v;
        }
    } else {
        #pragma unroll
        for (int p = 0; p < 8; ++p) {
            int el = p * 8 + w;
            int node = (l < 32) ? erow[el] : ecol[el];
            int f0 = (l & 31) * 4;
            float4 v = *(const float4*)(h + (size_t)node * D + f0);
            uint2 pk; pk.x = pk2bf(v.x, v.y); pk.y = pk2bf(v.z, v.w);
            *(uint2*)&A[el][(l >> 5) * 128 + f0] = pk;
        }
    }
    __syncthreads();

    // ---- layer 1: t1 = silu([hR|hC|dist] @ We1 + be1), hold in regs ----
    unsigned hold[4][2];
    #pragma unroll
    for (int mt = 0; mt < 4; ++mt) {
        bf16x8 a[8];
        #pragma unroll
        for (int kk = 0; kk < 8; ++kk)
            a[kk] = *(const bf16x8*)&A[mt*16 + m][kk*32 + q*8];
        f32x4 c;
        #pragma unroll
        for (int rg = 0; rg < 4; ++rg)
            c[rg] = fmaf(edist[mt*16 + q*4 + rg], wr1, b1_);
        #pragma unroll
        for (int kk = 0; kk < 8; ++kk)
            c = __builtin_amdgcn_mfma_f32_16x16x32_bf16(a[kk], B1[kk], c, 0, 0, 0);
        hold[mt][0] = pk2bf(silu_f(c[0]), silu_f(c[1]));
        hold[mt][1] = pk2bf(silu_f(c[2]), silu_f(c[3]));
    }
    __syncthreads();   // all h_col reads done before T overlay writes

    #pragma unroll
    for (int mt = 0; mt < 4; ++mt) {
        int n = 128 + w*16 + m;
        int rb = mt*16 + q*4;
        unsigned h0 = hold[mt][0], h1 = hold[mt][1];
        A[rb + 0][n] = (u16)h0;
        A[rb + 1][n] = (u16)(h0 >> 16);
        A[rb + 2][n] = (u16)h1;
        A[rb + 3][n] = (u16)(h1 >> 16);
    }
    __syncthreads();

    // ---- layer 2: msg = silu(t1 @ We2 + be2); T (cols 128+) -> msg (cols 0..127) ----
    {
        bf16x8 Bf[4];
        #pragma unroll
        for (int kk = 0; kk < 4; ++kk)
            Bf[kk] = *(const bf16x8*)&We2F[((w*4 + kk)*64 + l)*8];
        float b0 = be2[w*16 + m];
        #pragma unroll
        for (int mt = 0; mt < 4; ++mt) {
            bf16x8 a[4];
            #pragma unroll
            for (int kk = 0; kk < 4; ++kk)
                a[kk] = *(const bf16x8*)&A[mt*16 + m][128 + kk*32 + q*8];
            f32x4 c = { b0, b0, b0, b0 };
            #pragma unroll
            for (int kk = 0; kk < 4; ++kk)
                c = __builtin_amdgcn_mfma_f32_16x16x32_bf16(a[kk], Bf[kk], c, 0, 0, 0);
            int n = w*16 + m;
            int rb = mt*16 + q*4;
            unsigned p0 = pk2bf(silu_f(c[0]), silu_f(c[1]));
            unsigned p1 = pk2bf(silu_f(c[2]), silu_f(c[3]));
            A[rb + 0][n] = (u16)p0;
            A[rb + 1][n] = (u16)(p0 >> 16);
            A[rb + 2][n] = (u16)p1;
            A[rb + 3][n] = (u16)(p1 >> 16);
        }
    }
    __syncthreads();

    // ---- coord (fused): w_e = clip(silu(msg @ Wc1 + bc1) . Wc2, -1, 1) ----
    // thread holds t2 for 4 edges x 1 feature; scale by Wc2[n], shfl-reduce
    // over the 16 m-lanes, stash per-wave partial in esum.
    {
        bf16x8 Bf[4];
        #pragma unroll
        for (int kk = 0; kk < 4; ++kk)
            Bf[kk] = *(const bf16x8*)&Wc1F[((w*4 + kk)*64 + l)*8];
        float b0 = bc1[w*16 + m];
        float wc2 = Wc2[w*16 + m];
        #pragma unroll
        for (int mt = 0; mt < 4; ++mt) {
            bf16x8 a[4];
            #pragma unroll
            for (int kk = 0; kk < 4; ++kk)
                a[kk] = *(const bf16x8*)&A[mt*16 + m][kk*32 + q*8];
            f32x4 c = { b0, b0, b0, b0 };
            #pragma unroll
            for (int kk = 0; kk < 4; ++kk)
                c = __builtin_amdgcn_mfma_f32_16x16x32_bf16(a[kk], Bf[kk], c, 0, 0, 0);
            float part[4];
            #pragma unroll
            for (int rg = 0; rg < 4; ++rg) part[rg] = silu_f(c[rg]) * wc2;
            #pragma unroll
            for (int rg = 0; rg < 4; ++rg) {
                part[rg] += __shfl_xor(part[rg], 1);
                part[rg] += __shfl_xor(part[rg], 2);
                part[rg] += __shfl_xor(part[rg], 4);
                part[rg] += __shfl_xor(part[rg], 8);
            }
            if (m == 0)
                *(float4*)&esum[w][mt*16 + q*4] =
                    make_float4(part[0], part[1], part[2], part[3]);
        }
    }
    __syncthreads();

    // per-edge coord weight (cross-wave sum) + pos handling
    if (tid < 64) {
        float p = 0.f;
        #pragma unroll
        for (int w2 = 0; w2 < 8; ++w2) p += esum[w2][tid];
        float cw = fminf(1.0f, fmaxf(-1.0f, p));
        if (SORT) {
            es[tid] = cw / edist[tid];
        } else if ((e0 + tid) < E) {
            float s = cw / edist[tid];
            int r = erow[tid];
            atomicAdd(&pos_out[r*3+0], ediff[tid][0] * s);
            atomicAdd(&pos_out[r*3+1], ediff[tid][1] * s);
            atomicAdd(&pos_out[r*3+2], ediff[tid][2] * s);
        }
    }
    __syncthreads();

    // ---- tail: agg (+pos) scatter from LDS msg — wave w owns edges [8w, 8w+8) ----
    if (SORT) {
        int cur_r = -1;
        float a0 = 0.f, a1 = 0.f, pc = 0.f;
        for (int e2 = 0; e2 < 8; ++e2) {
            int e = w * 8 + e2;
            if (e0 + e >= E) break;        // uniform across wave
            int r = erow[e];
            if (r != cur_r) {               // uniform across wave
                if (cur_r >= 0) {
                    pk_agg_add(&aggb[(size_t)cur_r * D + l * 2], pk2bf(a0, a1));
                    if (l < 3) atomicAdd(&pos_out[cur_r * 3 + l], pc);
                }
                cur_r = r; a0 = 0.f; a1 = 0.f; pc = 0.f;
            }
            unsigned pk = *(const unsigned*)&A[e][l * 2];
            a0 += bf2f((u16)pk);
            a1 += bf2f((u16)(pk >> 16));
            if (l < 3) pc += ediff[e][l] * es[e];
        }
        if (cur_r >= 0) {
            pk_agg_add(&aggb[(size_t)cur_r * D + l * 2], pk2bf(a0, a1));
            if (l < 3) atomicAdd(&pos_out[cur_r * 3 + l], pc);
        }
    } else if (BA) {
        #pragma unroll
        for (int e2 = 0; e2 < 8; ++e2) {
            int e = w * 8 + e2;
            if ((e0 + e) < E) {
                int r = erow[e];
                unsigned pk = *(const unsigned*)&A[e][l * 2];
                pk_agg_add(&aggb[(size_t)r * D + l * 2], pk);
            }
        }
    } else {
        #pragma unroll
        for (int e2 = 0; e2 < 8; ++e2) {
            int e = w * 8 + e2;
            if ((e0 + e) < E) {
                int r = erow[e];
                atomicAdd(&aggf[(size_t)r * D + l],      bf2f(A[e][l]));
                atomicAdd(&aggf[(size_t)r * D + l + 64], bf2f(A[e][l + 64]));
            }
        }
    }
}

// ---------------- node kernel: h_out = h + MLP([h|agg]) ----------------
template<int BA, int HB>
__global__ __launch_bounds__(256, 4) void egnn_node_mfma(
    const float* __restrict__ h, const u16* __restrict__ hb,
    const u16* __restrict__ aggb, const float* __restrict__ aggf,
    const u16* __restrict__ Wn1F, const float* __restrict__ bn1,
    const u16* __restrict__ Wn2F, const float* __restrict__ bn2,
    float* __restrict__ out, int N)
{
    __shared__ u16 A[64][264];

    const int tid = threadIdx.x;
    const int w = tid >> 6, l = tid & 63;
    const int q = l >> 4, m = l & 15;
    const int n0 = blockIdx.x * 64;

    bf16x8 B1[2][8];
    #pragma unroll
    for (int t2 = 0; t2 < 2; ++t2)
        #pragma unroll
        for (int kk = 0; kk < 8; ++kk)
            B1[t2][kk] = *(const bf16x8*)&Wn1F[(((2*w + t2)*8 + kk)*64 + l)*8];

    // gather [h | agg] -> bf16 LDS
    if (BA && HB) {
        #pragma unroll
        for (int p = 0; p < 8; ++p) {
            int c = p * 256 + tid;
            int el = c >> 5;
            int half = (c >> 4) & 1;
            int f0 = (c & 15) * 8;              // u16 units, 16B per chunk
            int node = n0 + el; if (node >= N) node = N - 1;
            const u16* src = half ? &aggb[(size_t)node * D + f0]
                                  : &hb[(size_t)node * D + f0];
            *(uint4*)&A[el][half * 128 + f0] = *(const uint4*)src;
        }
    } else {
        #pragma unroll
        for (int p = 0; p < 16; ++p) {
            int nl = p * 4 + w;
            int node = n0 + nl; if (node >= N) node = N - 1;
            int f0 = (l & 31) * 4;
            if (l < 32) {
                if (HB) {
                    *(u16x4*)&A[nl][f0] = *(const u16x4*)&hb[(size_t)node * D + f0];
                } else {
                    float4 v = *(const float4*)(h + (size_t)node * D + f0);
                    uint2 pk; pk.x = pk2bf(v.x, v.y); pk.y = pk2bf(v.z, v.w);
                    *(uint2*)&A[nl][f0] = pk;
                }
            } else if (BA) {
                u16x4 v = *(const u16x4*)&aggb[(size_t)node * D + f0];
                *(u16x4*)&A[nl][128 + f0] = v;
            } else {
                float4 v = *(const float4*)(aggf + (size_t)node * D + f0);
                uint2 pk; pk.x = pk2bf(v.x, v.y); pk.y = pk2bf(v.z, v.w);
                *(uint2*)&A[nl][128 + f0] = pk;
            }
        }
    }
    __syncthreads();

    // ---- node layer 1: hold in regs, then overlay T onto agg half ----
    unsigned hold[4][2][2];
    {
        float b0[2];
        #pragma unroll
        for (int t2 = 0; t2 < 2; ++t2) b0[t2] = bn1[(2*w + t2)*16 + m];
        #pragma unroll
        for (int mt = 0; mt < 4; ++mt) {
            bf16x8 a[8];
            #pragma unroll
            for (int kk = 0; kk < 8; ++kk)
                a[kk] = *(const bf16x8*)&A[mt*16 + m][kk*32 + q*8];
            #pragma unroll
            for (int t2 = 0; t2 < 2; ++t2) {
                f32x4 c = { b0[t2], b0[t2], b0[t2], b0[t2] };
                #pragma unroll
                for (int kk = 0; kk < 8; ++kk)
                    c = __builtin_amdgcn_mfma_f32_16x16x32_bf16(a[kk], B1[t2][kk], c, 0, 0, 0);
                hold[mt][t2][0] = pk2bf(silu_f(c[0]), silu_f(c[1]));
                hold[mt][t2][1] = pk2bf(silu_f(c[2]), silu_f(c[3]));
            }
        }
    }
    __syncthreads();

    #pragma unroll
    for (int mt = 0; mt < 4; ++mt)
        #pragma unroll
        for (int t2 = 0; t2 < 2; ++t2) {
            int n = 128 + (2*w + t2)*16 + m;
            int rb = mt*16 + q*4;
            unsigned h0 = hold[mt][t2][0], h1 = hold[mt][t2][1];
            A[rb + 0][n] = (u16)h0;
            A[rb + 1][n] = (u16)(h0 >> 16);
            A[rb + 2][n] = (u16)h1;
            A[rb + 3][n] = (u16)(h1 >> 16);
        }
    __syncthreads();

    // ---- node layer 2 + residual: out = h + t1 @ Wn2 + bn2 (h from LDS bf16) ----
    {
        bf16x8 Bf[2][4];
        #pragma unroll
        for (int t2 = 0; t2 < 2; ++t2)
            #pragma unroll
            for (int kk = 0; kk < 4; ++kk)
                Bf[t2][kk] = *(const bf16x8*)&Wn2F[(((2*w + t2)*4 + kk)*64 + l)*8];
        float b0[2];
        #pragma unroll
        for (int t2 = 0; t2 < 2; ++t2) b0[t2] = bn2[(2*w + t2)*16 + m];
        #pragma unroll
        for (int mt = 0; mt < 4; ++mt) {
            bf16x8 a[4];
            #pragma unroll
            for (int kk = 0; kk < 4; ++kk)
                a[kk] = *(const bf16x8*)&A[mt*16 + m][128 + kk*32 + q*8];
            #pragma unroll
            for (int t2 = 0; t2 < 2; ++t2) {
                f32x4 c = { b0[t2], b0[t2], b0[t2], b0[t2] };
                #pragma unroll
                for (int kk = 0; kk < 4; ++kk)
                    c = __builtin_amdgcn_mfma_f32_16x16x32_bf16(a[kk], Bf[t2][kk], c, 0, 0, 0);
                int n = (2*w + t2)*16 + m;
                #pragma unroll
                for (int rg = 0; rg < 4; ++rg) {
                    int node = n0 + mt*16 + q*4 + rg;
                    if (node < N)
                        out[(size_t)node * D + n] =
                            bf2f(A[mt*16 + q*4 + rg][n]) + c[rg];
                }
            }
        }
    }
}

extern "C" void kernel_launch(void* const* d_in, const int* in_sizes, int n_in,
                              void* d_out, int out_size, void* d_ws, size_t ws_size,
                              hipStream_t stream)
{
    const float* h   = (const float*)d_in[0];
    const float* pos = (const float*)d_in[1];
    const int*   eidx= (const int*)d_in[2];
    const float* We1 = (const float*)d_in[3];
    const float* be1 = (const float*)d_in[4];
    const float* We2 = (const float*)d_in[5];
    const float* be2 = (const float*)d_in[6];
    const float* Wn1 = (const float*)d_in[7];
    const float* bn1 = (const float*)d_in[8];
    const float* Wn2 = (const float*)d_in[9];
    const float* bn2 = (const float*)d_in[10];
    const float* Wc1 = (const float*)d_in[11];
    const float* bc1 = (const float*)d_in[12];
    const float* Wc2 = (const float*)d_in[13];

    const int N = in_sizes[0] / D;
    const int E = in_sizes[2] / 2;

    float* out     = (float*)d_out;
    float* pos_out = out + (size_t)N * D;

    u16* ws = (u16*)d_ws;
    const u16* We1F = ws + FRAG_WE1;
    const u16* We2F = ws + FRAG_WE2;
    const u16* Wc1F = ws + FRAG_WC1;
    const u16* Wn1F = ws + FRAG_WN1;
    const u16* Wn2F = ws + FRAG_WN2;
    const float* We1r = (const float*)(ws + WE1R_OFF);

    u16*   aggb = ws + AGG_OFF;
    u16*   hb   = ws + AGG_OFF + (size_t)N * D;   // bf16 h table (HB path)
    u32*   deg  = (u32*)(ws + AGG_OFF + 2 * (size_t)N * D);
    u32*   cur  = deg + N;
    uint2* rc   = (uint2*)(cur + N);
    float* aggf = out;   // fallback: fp32 agg in out h-region

    const size_t need_ba   = ((size_t)AGG_OFF + (size_t)N * D) * 2;
    const size_t need_hb   = ((size_t)AGG_OFF + 2 * (size_t)N * D) * 2;
    const size_t need_sort = need_hb + (2 * (size_t)N + 2 * (size_t)E) * 4;

    const int NB = (N + 1023) / 1024;
    const int ntiles = (E + 63) / 64;

    if (ws_size >= need_sort) {
        hipMemsetAsync(deg, 0, (size_t)N * sizeof(u32), stream);
        egnn_setup<<<2048, 256, 0, stream>>>(h, pos, eidx, We1, We2, Wc1, Wn1, Wn2,
                                             out, ws, deg, E, N);
        egnn_scan<<<NB, 256, 0, stream>>>(deg, cur, N);
        egnn_scatter<<<(E + 255) / 256, 256, 0, stream>>>(eidx, cur, rc, E);
        egnn_edge_mfma<1, 1, 1><<<ntiles, 512, 0, stream>>>(
            h, hb, pos, eidx, rc, We1F, We1r, be1, We2F, be2, Wc1F, bc1, Wc2,
            aggb, aggf, pos_out, E);
        egnn_node_mfma<1, 1><<<(N + 63) / 64, 256, 0, stream>>>(
            h, hb, aggb, aggf, Wn1F, bn1, Wn2F, bn2, out, N);
    } else if (ws_size >= need_hb) {
        egnn_setup<<<2048, 256, 0, stream>>>(h, pos, eidx, We1, We2, Wc1, Wn1, Wn2,
                                             out, ws, deg, 0, N);
        egnn_edge_mfma<1, 1, 0><<<ntiles, 512, 0, stream>>>(
            h, hb, pos, eidx, rc, We1F, We1r, be1, We2F, be2, Wc1F, bc1, Wc2,
            aggb, aggf, pos_out, E);
        egnn_node_mfma<1, 1><<<(N + 63) / 64, 256, 0, stream>>>(
            h, hb, aggb, aggf, Wn1F, bn1, Wn2F, bn2, out, N);
    } else if (ws_size >= need_ba) {
        egnn_prep<<<128, 256, 0, stream>>>(We1, We2, Wc1, Wn1, Wn2, ws);
        egnn_init_ba<<<2048, 256, 0, stream>>>(pos, out, (uint4*)aggb, N);
        egnn_edge_mfma<1, 0, 0><<<ntiles, 512, 0, stream>>>(
            h, hb, pos, eidx, rc, We1F, We1r, be1, We2F, be2, Wc1F, bc1, Wc2,
            aggb, aggf, pos_out, E);
        egnn_node_mfma<1, 0><<<(N + 63) / 64, 256, 0, stream>>>(
            h, hb, aggb, aggf, Wn1F, bn1, Wn2F, bn2, out, N);
    } else {
        egnn_prep<<<128, 256, 0, stream>>>(We1, We2, Wc1, Wn1, Wn2, ws);
        egnn_init_f32<<<2048, 256, 0, stream>>>(pos, out, N);
        egnn_edge_mfma<0, 0, 0><<<ntiles, 512, 0, stream>>>(
            h, hb, pos, eidx, rc, We1F, We1r, be1, We2F, be2, Wc1F, bc1, Wc2,
            aggb, aggf, pos_out, E);
        egnn_node_mfma<0, 0><<<(N + 63) / 64, 256, 0, stream>>>(
            h, hb, aggb, aggf, Wn1F, bn1, Wn2F, bn2, out, N);
    }
}

// Round 11
// 396.611 us; speedup vs baseline: 1.0780x; 1.0780x over previous
//
#include <hip/hip_runtime.h>
#include <hip/hip_bf16.h>
#include <math.h>
#include <stdint.h>

#define D 128

typedef unsigned short u16;
typedef unsigned int u32;
typedef __attribute__((ext_vector_type(8))) short bf16x8;
typedef __attribute__((ext_vector_type(4))) float f32x4;
typedef __attribute__((ext_vector_type(4))) unsigned short u16x4;

// ws layout in u16 units:
#define FRAG_WE1 0
#define FRAG_WE2 32768
#define FRAG_WC1 49152
#define FRAG_WN1 65536
#define FRAG_WN2 98304
#define WE1R_OFF 114688   // float[128] = 256 u16
#define AGG_OFF  131072   // bf16 agg[N*D] (BA path)
// bf16 h table (HB path) at AGG_OFF + N*D
// sort arrays (SORT path) after hb: u32 deg[N], u32 cur[N], uint2 rc[E]

__device__ __forceinline__ float silu_f(float x) {
    // x * rcp(1+exp(-x)) — bf16 output tolerates 1-ulp rcp
    return x * __builtin_amdgcn_rcpf(1.0f + __expf(-x));
}
__device__ __forceinline__ u16 f2bf(float x) {
    union { float f; unsigned int u; } v; v.f = x;
    unsigned int r = v.u + 0x7fffu + ((v.u >> 16) & 1u);
    return (u16)(r >> 16);
}
__device__ __forceinline__ float bf2f(u16 u) {
    union { unsigned int u; float f; } v; v.u = ((unsigned int)u) << 16; return v.f;
}
__device__ __forceinline__ unsigned pk2bf(float a, float b) {
    union { __hip_bfloat162 v; unsigned u; } u;
    u.v = __float22bfloat162_rn(make_float2(a, b));
    return u.u;
}
// packed bf16 atomic add — raw asm (clang builtin removed on ROCm 7)
__device__ __forceinline__ void pk_agg_add(u16* addr, unsigned packed) {
    asm volatile("global_atomic_pk_add_bf16 %0, %1, off"
                 :: "v"(addr), "v"(packed) : "memory");
}

// ---------------- prep: weights -> fragment-ordered bf16 (fallback tiers) ----------------
// B-frag: elem(nt,kk,lane,j) = W[k*128+n], k = kk*32+(lane>>4)*8+j, n = nt*16+(lane&15)
__global__ __launch_bounds__(256) void egnn_prep(
    const float* __restrict__ We1, const float* __restrict__ We2,
    const float* __restrict__ Wc1, const float* __restrict__ Wn1,
    const float* __restrict__ Wn2, u16* __restrict__ ws)
{
    int i = blockIdx.x * blockDim.x + threadIdx.x;   // 32768 threads
    u16* We1F = ws + FRAG_WE1;
    u16* We2F = ws + FRAG_WE2;
    u16* Wc1F = ws + FRAG_WC1;
    u16* Wn1F = ws + FRAG_WN1;
    u16* Wn2F = ws + FRAG_WN2;
    float* We1r = (float*)(ws + WE1R_OFF);

    if (i < 32768) {
        int j = i & 7, l = (i >> 3) & 63, kk = (i >> 9) & 7, nt = i >> 12;
        int k = kk * 32 + (l >> 4) * 8 + j;
        int n = nt * 16 + (l & 15);
        We1F[i] = f2bf(We1[k * D + n]);
        Wn1F[i] = f2bf(Wn1[k * D + n]);
    }
    if (i < 16384) {
        int j = i & 7, l = (i >> 3) & 63, kk = (i >> 9) & 3, nt = i >> 11;
        int k = kk * 32 + (l >> 4) * 8 + j;
        int n = nt * 16 + (l & 15);
        We2F[i] = f2bf(We2[k * D + n]);
        Wc1F[i] = f2bf(Wc1[k * D + n]);
        Wn2F[i] = f2bf(Wn2[k * D + n]);
    }
    if (i < 128) We1r[i] = We1[256 * D + i];
}

// ---------------- setup (fused): weights + zero agg + bf16 h table + pos + row count ----------------
// deg must be pre-zeroed (hipMemsetAsync) when ecount > 0.
__global__ __launch_bounds__(256) void egnn_setup(
    const float* __restrict__ h, const float* __restrict__ pos,
    const int* __restrict__ eidx,
    const float* __restrict__ We1, const float* __restrict__ We2,
    const float* __restrict__ Wc1, const float* __restrict__ Wn1,
    const float* __restrict__ Wn2,
    float* __restrict__ out, u16* __restrict__ ws,
    u32* __restrict__ deg, int ecount, int N)
{
    u16* We1F = ws + FRAG_WE1;
    u16* We2F = ws + FRAG_WE2;
    u16* Wc1F = ws + FRAG_WC1;
    u16* Wn1F = ws + FRAG_WN1;
    u16* Wn2F = ws + FRAG_WN2;
    float* We1r = (float*)(ws + WE1R_OFF);
    uint4* agg4 = (uint4*)(ws + AGG_OFF);
    uint2* hb2  = (uint2*)(ws + AGG_OFF + (size_t)N * D);

    const int nagg = N * D / 8;
    const int nh   = N * D / 4;
    const int bw   = 49280;                 // 32768 + 16384 + 128
    const int total = bw + nagg + nh + N * 3 + ecount;
    int stride = gridDim.x * blockDim.x;
    for (int i = blockIdx.x * blockDim.x + threadIdx.x; i < total; i += stride) {
        if (i < 32768) {
            int j = i & 7, l = (i >> 3) & 63, kk = (i >> 9) & 7, nt = i >> 12;
            int k = kk * 32 + (l >> 4) * 8 + j;
            int n = nt * 16 + (l & 15);
            We1F[i] = f2bf(We1[k * D + n]);
            Wn1F[i] = f2bf(Wn1[k * D + n]);
        } else if (i < 49152) {
            int i2 = i - 32768;
            int j = i2 & 7, l = (i2 >> 3) & 63, kk = (i2 >> 9) & 3, nt = i2 >> 11;
            int k = kk * 32 + (l >> 4) * 8 + j;
            int n = nt * 16 + (l & 15);
            We2F[i2] = f2bf(We2[k * D + n]);
            Wc1F[i2] = f2bf(Wc1[k * D + n]);
            Wn2F[i2] = f2bf(Wn2[k * D + n]);
        } else if (i < bw) {
            int i2 = i - 49152;
            We1r[i2] = We1[256 * D + i2];
        } else {
            int k = i - bw;
            if (k < nagg) {
                agg4[k] = make_uint4(0, 0, 0, 0);
            } else if (k < nagg + nh) {
                int j = k - nagg;
                float4 v = ((const float4*)h)[j];
                uint2 p; p.x = pk2bf(v.x, v.y); p.y = pk2bf(v.z, v.w);
                hb2[j] = p;
            } else if (k < nagg + nh + N * 3) {
                int j = k - nagg - nh;
                out[(size_t)N * D + j] = pos[j];
            } else {
                int j = k - nagg - nh - N * 3;   // fused row histogram
                atomicAdd(&deg[eidx[j]], 1u);
            }
        }
    }
}

// ---------------- init (BA): zero bf16 agg in ws, copy pos -> pos_out ----------------
__global__ __launch_bounds__(256) void egnn_init_ba(
    const float* __restrict__ pos, float* __restrict__ out,
    uint4* __restrict__ agg4, int N)
{
    int stride = gridDim.x * blockDim.x;
    int nagg = N * D / 8;
    int total = nagg + N * 3;
    for (int i = blockIdx.x * blockDim.x + threadIdx.x; i < total; i += stride) {
        if (i < nagg) agg4[i] = make_uint4(0, 0, 0, 0);
        else { int j = i - nagg; out[(size_t)N * D + j] = pos[j]; }
    }
}

// ---------------- init (fallback): zero fp32 agg (= out h region), copy pos ----------------
__global__ __launch_bounds__(256) void egnn_init_f32(
    const float* __restrict__ pos, float* __restrict__ out, int N)
{
    int stride = gridDim.x * blockDim.x;
    int hd = N * D;
    int total = hd + N * 3;
    for (int i = blockIdx.x * blockDim.x + threadIdx.x; i < total; i += stride)
        out[i] = (i < hd) ? 0.0f : pos[i - hd];
}

// ---------------- sort: single-dispatch exclusive scan ----------------
// Block b redundantly sums deg[0, b*1024) straight from L2 (<=196KB, cheap),
// then ex-scans its own 1024-chunk. Replaces scan_a+scan_b (one dispatch less).
__global__ __launch_bounds__(256) void egnn_scan(
    const u32* __restrict__ deg, u32* __restrict__ cur, int N)
{
    __shared__ u32 pred[4];
    __shared__ u32 woff[4];
    int b = blockIdx.x, t = threadIdx.x;
    int lane = t & 63;

    // prefix over [0, b*1024): strided quad sums (P is a multiple of 1024)
    u32 pre = 0;
    int P = b << 10;
    for (int i = t * 4; i < P; i += 1024) {
        uint4 v = *(const uint4*)&deg[i];
        pre += v.x + v.y + v.z + v.w;
    }
    #pragma unroll
    for (int off = 1; off < 64; off <<= 1) pre += __shfl_xor(pre, off);
    if (lane == 0) pred[t >> 6] = pre;
    __syncthreads();
    u32 blockpre = pred[0] + pred[1] + pred[2] + pred[3];

    // local chunk ex-scan
    int i0 = P + t * 4;
    u32 d[4]; u32 s = 0;
    #pragma unroll
    for (int k = 0; k < 4; ++k) { int i = i0 + k; d[k] = (i < N) ? deg[i] : 0u; s += d[k]; }
    u32 incl = s;
    for (int off = 1; off < 64; off <<= 1) {
        u32 v = __shfl_up(incl, off);
        if (lane >= off) incl += v;
    }
    if (lane == 63) woff[t >> 6] = incl;
    __syncthreads();
    u32 ws_ = 0;
    for (int w2 = 0; w2 < (t >> 6); ++w2) ws_ += woff[w2];
    u32 ex = blockpre + ws_ + incl - s;
    #pragma unroll
    for (int k = 0; k < 4; ++k) { int i = i0 + k; if (i < N) cur[i] = ex; ex += d[k]; }
}

// ---------------- sort: scatter (row,col) pairs into row-sorted rc ----------------
__global__ __launch_bounds__(256) void egnn_scatter(
    const int* __restrict__ eidx, u32* __restrict__ cur,
    uint2* __restrict__ rc, int E)
{
    int i = blockIdx.x * blockDim.x + threadIdx.x;
    if (i < E) {
        u32 r = (u32)eidx[i];
        u32 c = (u32)eidx[E + i];
        u32 p = atomicAdd(&cur[r], 1u);
        rc[p] = make_uint2(r, c);
    }
}

// ---------------- edge kernel (R9 structure — proven 214 µs) ----------------
// 8 waves (512 thr) per 64-edge tile; 4 blocks/CU = ~100% occupancy.
// One block per tile, in dispatch order (grid-stride broke L2 locality, R8).
// Coord path kept as C1-transpose + coord2 stage (R10's shfl-fusion regressed:
// serial dependent shfl chains stall; VALU 61->49 while dur rose).
// SORT=1: row-sorted rc[]; tail = segmented fp32 run-reduction + pk-atomics.
template<int BA, int HB, int SORT>
__global__ __launch_bounds__(512, 8) void egnn_edge_mfma(
    const float* __restrict__ h, const u16* __restrict__ hb,
    const float* __restrict__ pos,
    const int* __restrict__ eidx, const uint2* __restrict__ rc,
    const u16* __restrict__ We1F, const float* __restrict__ We1r,
    const float* __restrict__ be1,
    const u16* __restrict__ We2F, const float* __restrict__ be2,
    const u16* __restrict__ Wc1F, const float* __restrict__ bc1,
    const float* __restrict__ Wc2,
    u16* __restrict__ aggb, float* __restrict__ aggf,
    float* __restrict__ pos_out, int E)
{
    __shared__ u16 A[64][264];
    __shared__ int erow[64], ecol[64];
    __shared__ float ediff[64][3], edist[64];
    __shared__ float es[64];   // SORT: per-edge coord scale cw/dist

    const int tid = threadIdx.x;
    const int w = tid >> 6, l = tid & 63;    // 8 waves
    const int q = l >> 4, m = l & 15;
    const int e0 = blockIdx.x * 64;

    if (tid < 64) {
        int e = e0 + tid;
        int r = 0, c = 0;
        if (e < E) {
            if (SORT) { uint2 p = rc[e]; r = (int)p.x; c = (int)p.y; }
            else { r = eidx[e]; c = eidx[E + e]; }
        }
        erow[tid] = r; ecol[tid] = c;
        float dx = pos[r*3+0] - pos[c*3+0];
        float dy = pos[r*3+1] - pos[c*3+1];
        float dz = pos[r*3+2] - pos[c*3+2];
        float dd = fmaxf(sqrtf(dx*dx + dy*dy + dz*dz), 1e-6f);
        ediff[tid][0] = dx; ediff[tid][1] = dy; ediff[tid][2] = dz;
        edist[tid] = dd;
    }
    __syncthreads();

    // hoist layer-1 B-frags (single 16-col tile per wave -> 8 frags, reg-resident)
    bf16x8 B1[8];
    #pragma unroll
    for (int kk = 0; kk < 8; ++kk)
        B1[kk] = *(const bf16x8*)&We1F[((w*8 + kk)*64 + l)*8];
    float b1_ = be1[w*16 + m];
    float wr1 = We1r[w*16 + m];

    // gather h[row] | h[col] -> bf16 LDS
    if (HB) {
        // 2048 16B-chunks per tile, 512 threads -> 4 iters
        #pragma unroll
        for (int p = 0; p < 4; ++p) {
            int c = p * 512 + tid;
            int el = c >> 5;
            int half = (c >> 4) & 1;
            int f0 = (c & 15) * 8;              // u16 units, 16B per chunk
            int node = half ? ecol[el] : erow[el];
            uint4 v = *(const uint4*)(hb + (size_t)node * D + f0);
            *(uint4*)&A[el][half * 128 + f0] = v;
        }
    } else {
        #pragma unroll
        for (int p = 0; p < 8; ++p) {
            int el = p * 8 + w;
            int node = (l < 32) ? erow[el] : ecol[el];
            int f0 = (l & 31) * 4;
            float4 v = *(const float4*)(h + (size_t)node * D + f0);
            uint2 pk; pk.x = pk2bf(v.x, v.y); pk.y = pk2bf(v.z, v.w);
            *(uint2*)&A[el][(l >> 5) * 128 + f0] = pk;
        }
    }
    __syncthreads();

    // ---- layer 1: t1 = silu([hR|hC|dist] @ We1 + be1), hold in regs ----
    unsigned hold[4][2];
    #pragma unroll
    for (int mt = 0; mt < 4; ++mt) {
        bf16x8 a[8];
        #pragma unroll
        for (int kk = 0; kk < 8; ++kk)
            a[kk] = *(const bf16x8*)&A[mt*16 + m][kk*32 + q*8];
        f32x4 c;
        #pragma unroll
        for (int rg = 0; rg < 4; ++rg)
            c[rg] = fmaf(edist[mt*16 + q*4 + rg], wr1, b1_);
        #pragma unroll
        for (int kk = 0; kk < 8; ++kk)
            c = __builtin_amdgcn_mfma_f32_16x16x32_bf16(a[kk], B1[kk], c, 0, 0, 0);
        hold[mt][0] = pk2bf(silu_f(c[0]), silu_f(c[1]));
        hold[mt][1] = pk2bf(silu_f(c[2]), silu_f(c[3]));
    }
    __syncthreads();   // all h_col reads done before T overlay writes

    #pragma unroll
    for (int mt = 0; mt < 4; ++mt) {
        int n = 128 + w*16 + m;
        int rb = mt*16 + q*4;
        unsigned h0 = hold[mt][0], h1 = hold[mt][1];
        A[rb + 0][n] = (u16)h0;
        A[rb + 1][n] = (u16)(h0 >> 16);
        A[rb + 2][n] = (u16)h1;
        A[rb + 3][n] = (u16)(h1 >> 16);
    }
    __syncthreads();

    // ---- layer 2: msg = silu(t1 @ We2 + be2); T (cols 128+) -> msg (cols 0..127) ----
    {
        bf16x8 Bf[4];
        #pragma unroll
        for (int kk = 0; kk < 4; ++kk)
            Bf[kk] = *(const bf16x8*)&We2F[((w*4 + kk)*64 + l)*8];
        float b0 = be2[w*16 + m];
        #pragma unroll
        for (int mt = 0; mt < 4; ++mt) {
            bf16x8 a[4];
            #pragma unroll
            for (int kk = 0; kk < 4; ++kk)
                a[kk] = *(const bf16x8*)&A[mt*16 + m][128 + kk*32 + q*8];
            f32x4 c = { b0, b0, b0, b0 };
            #pragma unroll
            for (int kk = 0; kk < 4; ++kk)
                c = __builtin_amdgcn_mfma_f32_16x16x32_bf16(a[kk], Bf[kk], c, 0, 0, 0);
            int n = w*16 + m;
            int rb = mt*16 + q*4;
            unsigned p0 = pk2bf(silu_f(c[0]), silu_f(c[1]));
            unsigned p1 = pk2bf(silu_f(c[2]), silu_f(c[3]));
            A[rb + 0][n] = (u16)p0;
            A[rb + 1][n] = (u16)(p0 >> 16);
            A[rb + 2][n] = (u16)p1;
            A[rb + 3][n] = (u16)(p1 >> 16);
        }
    }
    __syncthreads();

    // ---- coord layer 1: t2 = silu(msg @ Wc1 + bc1); msg -> T (cols 128+) ----
    {
        bf16x8 Bf[4];
        #pragma unroll
        for (int kk = 0; kk < 4; ++kk)
            Bf[kk] = *(const bf16x8*)&Wc1F[((w*4 + kk)*64 + l)*8];
        float b0 = bc1[w*16 + m];
        #pragma unroll
        for (int mt = 0; mt < 4; ++mt) {
            bf16x8 a[4];
            #pragma unroll
            for (int kk = 0; kk < 4; ++kk)
                a[kk] = *(const bf16x8*)&A[mt*16 + m][kk*32 + q*8];
            f32x4 c = { b0, b0, b0, b0 };
            #pragma unroll
            for (int kk = 0; kk < 4; ++kk)
                c = __builtin_amdgcn_mfma_f32_16x16x32_bf16(a[kk], Bf[kk], c, 0, 0, 0);
            int n = 128 + w*16 + m;
            int rb = mt*16 + q*4;
            unsigned p0 = pk2bf(silu_f(c[0]), silu_f(c[1]));
            unsigned p1 = pk2bf(silu_f(c[2]), silu_f(c[3]));
            A[rb + 0][n] = (u16)p0;
            A[rb + 1][n] = (u16)(p0 >> 16);
            A[rb + 2][n] = (u16)p1;
            A[rb + 3][n] = (u16)(p1 >> 16);
        }
    }
    __syncthreads();

    // ---- coord layer 2: w_e = clip(t2 . Wc2, -1, 1) ----
    {
        int e = tid >> 3;           // 8 lanes per edge
        int l4 = tid & 7;
        float p = 0.f;
        #pragma unroll
        for (int i = 0; i < 4; ++i) {
            int k = l4 * 16 + i * 4;
            u16x4 tv = *(const u16x4*)&A[e][128 + k];
            float4 wv = *(const float4*)&Wc2[k];
            p += bf2f(tv.x)*wv.x + bf2f(tv.y)*wv.y + bf2f(tv.z)*wv.z + bf2f(tv.w)*wv.w;
        }
        p += __shfl_xor(p, 1);
        p += __shfl_xor(p, 2);
        p += __shfl_xor(p, 4);
        if (l4 == 0) {
            float cw = fminf(1.0f, fmaxf(-1.0f, p));
            if (SORT) {
                es[e] = cw / edist[e];   // consumed by same wave in tail
            } else if ((e0 + e) < E) {
                float s = cw / edist[e];
                int r = erow[e];
                atomicAdd(&pos_out[r*3+0], ediff[e][0] * s);
                atomicAdd(&pos_out[r*3+1], ediff[e][1] * s);
                atomicAdd(&pos_out[r*3+2], ediff[e][2] * s);
            }
        }
    }

    // ---- tail: agg (+pos) scatter from LDS msg — wave w owns edges [8w, 8w+8) ----
    if (SORT) {
        int cur_r = -1;
        float a0 = 0.f, a1 = 0.f, pc = 0.f;
        for (int e2 = 0; e2 < 8; ++e2) {
            int e = w * 8 + e2;
            if (e0 + e >= E) break;        // uniform across wave
            int r = erow[e];
            if (r != cur_r) {               // uniform across wave
                if (cur_r >= 0) {
                    pk_agg_add(&aggb[(size_t)cur_r * D + l * 2], pk2bf(a0, a1));
                    if (l < 3) atomicAdd(&pos_out[cur_r * 3 + l], pc);
                }
                cur_r = r; a0 = 0.f; a1 = 0.f; pc = 0.f;
            }
            unsigned pk = *(const unsigned*)&A[e][l * 2];
            a0 += bf2f((u16)pk);
            a1 += bf2f((u16)(pk >> 16));
            if (l < 3) pc += ediff[e][l] * es[e];
        }
        if (cur_r >= 0) {
            pk_agg_add(&aggb[(size_t)cur_r * D + l * 2], pk2bf(a0, a1));
            if (l < 3) atomicAdd(&pos_out[cur_r * 3 + l], pc);
        }
    } else if (BA) {
        #pragma unroll
        for (int e2 = 0; e2 < 8; ++e2) {
            int e = w * 8 + e2;
            if ((e0 + e) < E) {
                int r = erow[e];
                unsigned pk = *(const unsigned*)&A[e][l * 2];
                pk_agg_add(&aggb[(size_t)r * D + l * 2], pk);
            }
        }
    } else {
        #pragma unroll
        for (int e2 = 0; e2 < 8; ++e2) {
            int e = w * 8 + e2;
            if ((e0 + e) < E) {
                int r = erow[e];
                atomicAdd(&aggf[(size_t)r * D + l],      bf2f(A[e][l]));
                atomicAdd(&aggf[(size_t)r * D + l + 64], bf2f(A[e][l + 64]));
            }
        }
    }
}

// ---------------- node kernel: h_out = h + MLP([h|agg]) ----------------
// R11: same 8-wave/512-thread transform as the edge kernel — 34KB LDS with
// 512 thr -> 4 blocks/CU = ~100% occupancy (was 50% at 256 thr).
template<int BA, int HB>
__global__ __launch_bounds__(512, 8) void egnn_node_mfma(
    const float* __restrict__ h, const u16* __restrict__ hb,
    const u16* __restrict__ aggb, const float* __restrict__ aggf,
    const u16* __restrict__ Wn1F, const float* __restrict__ bn1,
    const u16* __restrict__ Wn2F, const float* __restrict__ bn2,
    float* __restrict__ out, int N)
{
    __shared__ u16 A[64][264];

    const int tid = threadIdx.x;
    const int w = tid >> 6, l = tid & 63;    // 8 waves
    const int q = l >> 4, m = l & 15;
    const int n0 = blockIdx.x * 64;

    bf16x8 B1[8];
    #pragma unroll
    for (int kk = 0; kk < 8; ++kk)
        B1[kk] = *(const bf16x8*)&Wn1F[((w*8 + kk)*64 + l)*8];

    // gather [h | agg] -> bf16 LDS
    if (BA && HB) {
        // 2048 16B chunks / 512 threads -> 4 iters
        #pragma unroll
        for (int p = 0; p < 4; ++p) {
            int c = p * 512 + tid;
            int el = c >> 5;
            int half = (c >> 4) & 1;
            int f0 = (c & 15) * 8;              // u16 units, 16B per chunk
            int node = n0 + el; if (node >= N) node = N - 1;
            const u16* src = half ? &aggb[(size_t)node * D + f0]
                                  : &hb[(size_t)node * D + f0];
            *(uint4*)&A[el][half * 128 + f0] = *(const uint4*)src;
        }
    } else {
        #pragma unroll
        for (int p = 0; p < 8; ++p) {
            int nl = p * 8 + w;
            int node = n0 + nl; if (node >= N) node = N - 1;
            int f0 = (l & 31) * 4;
            if (l < 32) {
                if (HB) {
                    *(u16x4*)&A[nl][f0] = *(const u16x4*)&hb[(size_t)node * D + f0];
                } else {
                    float4 v = *(const float4*)(h + (size_t)node * D + f0);
                    uint2 pk; pk.x = pk2bf(v.x, v.y); pk.y = pk2bf(v.z, v.w);
                    *(uint2*)&A[nl][f0] = pk;
                }
            } else if (BA) {
                u16x4 v = *(const u16x4*)&aggb[(size_t)node * D + f0];
                *(u16x4*)&A[nl][128 + f0] = v;
            } else {
                float4 v = *(const float4*)(aggf + (size_t)node * D + f0);
                uint2 pk; pk.x = pk2bf(v.x, v.y); pk.y = pk2bf(v.z, v.w);
                *(uint2*)&A[nl][128 + f0] = pk;
            }
        }
    }
    __syncthreads();

    // ---- node layer 1: hold in regs, then overlay T onto agg half ----
    unsigned hold[4][2];
    {
        float b0 = bn1[w*16 + m];
        #pragma unroll
        for (int mt = 0; mt < 4; ++mt) {
            bf16x8 a[8];
            #pragma unroll
            for (int kk = 0; kk < 8; ++kk)
                a[kk] = *(const bf16x8*)&A[mt*16 + m][kk*32 + q*8];
            f32x4 c = { b0, b0, b0, b0 };
            #pragma unroll
            for (int kk = 0; kk < 8; ++kk)
                c = __builtin_amdgcn_mfma_f32_16x16x32_bf16(a[kk], B1[kk], c, 0, 0, 0);
            hold[mt][0] = pk2bf(silu_f(c[0]), silu_f(c[1]));
            hold[mt][1] = pk2bf(silu_f(c[2]), silu_f(c[3]));
        }
    }
    __syncthreads();

    #pragma unroll
    for (int mt = 0; mt < 4; ++mt) {
        int n = 128 + w*16 + m;
        int rb = mt*16 + q*4;
        unsigned h0 = hold[mt][0], h1 = hold[mt][1];
        A[rb + 0][n] = (u16)h0;
        A[rb + 1][n] = (u16)(h0 >> 16);
        A[rb + 2][n] = (u16)h1;
        A[rb + 3][n] = (u16)(h1 >> 16);
    }
    __syncthreads();

    // ---- node layer 2 + residual: out = h + t1 @ Wn2 + bn2 (h from LDS bf16) ----
    {
        bf16x8 Bf[4];
        #pragma unroll
        for (int kk = 0; kk < 4; ++kk)
            Bf[kk] = *(const bf16x8*)&Wn2F[((w*4 + kk)*64 + l)*8];
        float b0 = bn2[w*16 + m];
        #pragma unroll
        for (int mt = 0; mt < 4; ++mt) {
            bf16x8 a[4];
            #pragma unroll
            for (int kk = 0; kk < 4; ++kk)
                a[kk] = *(const bf16x8*)&A[mt*16 + m][128 + kk*32 + q*8];
            f32x4 c = { b0, b0, b0, b0 };
            #pragma unroll
            for (int kk = 0; kk < 4; ++kk)
                c = __builtin_amdgcn_mfma_f32_16x16x32_bf16(a[kk], Bf[kk], c, 0, 0, 0);
            int n = w*16 + m;
            #pragma unroll
            for (int rg = 0; rg < 4; ++rg) {
                int node = n0 + mt*16 + q*4 + rg;
                if (node < N)
                    out[(size_t)node * D + n] =
                        bf2f(A[mt*16 + q*4 + rg][n]) + c[rg];
            }
        }
    }
}

extern "C" void kernel_launch(void* const* d_in, const int* in_sizes, int n_in,
                              void* d_out, int out_size, void* d_ws, size_t ws_size,
                              hipStream_t stream)
{
    const float* h   = (const float*)d_in[0];
    const float* pos = (const float*)d_in[1];
    const int*   eidx= (const int*)d_in[2];
    const float* We1 = (const float*)d_in[3];
    const float* be1 = (const float*)d_in[4];
    const float* We2 = (const float*)d_in[5];
    const float* be2 = (const float*)d_in[6];
    const float* Wn1 = (const float*)d_in[7];
    const float* bn1 = (const float*)d_in[8];
    const float* Wn2 = (const float*)d_in[9];
    const float* bn2 = (const float*)d_in[10];
    const float* Wc1 = (const float*)d_in[11];
    const float* bc1 = (const float*)d_in[12];
    const float* Wc2 = (const float*)d_in[13];

    const int N = in_sizes[0] / D;
    const int E = in_sizes[2] / 2;

    float* out     = (float*)d_out;
    float* pos_out = out + (size_t)N * D;

    u16* ws = (u16*)d_ws;
    const u16* We1F = ws + FRAG_WE1;
    const u16* We2F = ws + FRAG_WE2;
    const u16* Wc1F = ws + FRAG_WC1;
    const u16* Wn1F = ws + FRAG_WN1;
    const u16* Wn2F = ws + FRAG_WN2;
    const float* We1r = (const float*)(ws + WE1R_OFF);

    u16*   aggb = ws + AGG_OFF;
    u16*   hb   = ws + AGG_OFF + (size_t)N * D;   // bf16 h table (HB path)
    u32*   deg  = (u32*)(ws + AGG_OFF + 2 * (size_t)N * D);
    u32*   cur  = deg + N;
    uint2* rc   = (uint2*)(cur + N);
    float* aggf = out;   // fallback: fp32 agg in out h-region

    const size_t need_ba   = ((size_t)AGG_OFF + (size_t)N * D) * 2;
    const size_t need_hb   = ((size_t)AGG_OFF + 2 * (size_t)N * D) * 2;
    const size_t need_sort = need_hb + (2 * (size_t)N + 2 * (size_t)E) * 4;

    const int NB = (N + 1023) / 1024;
    const int ntiles = (E + 63) / 64;

    if (ws_size >= need_sort) {
        hipMemsetAsync(deg, 0, (size_t)N * sizeof(u32), stream);
        egnn_setup<<<2048, 256, 0, stream>>>(h, pos, eidx, We1, We2, Wc1, Wn1, Wn2,
                                             out, ws, deg, E, N);
        egnn_scan<<<NB, 256, 0, stream>>>(deg, cur, N);
        egnn_scatter<<<(E + 255) / 256, 256, 0, stream>>>(eidx, cur, rc, E);
        egnn_edge_mfma<1, 1, 1><<<ntiles, 512, 0, stream>>>(
            h, hb, pos, eidx, rc, We1F, We1r, be1, We2F, be2, Wc1F, bc1, Wc2,
            aggb, aggf, pos_out, E);
        egnn_node_mfma<1, 1><<<(N + 63) / 64, 512, 0, stream>>>(
            h, hb, aggb, aggf, Wn1F, bn1, Wn2F, bn2, out, N);
    } else if (ws_size >= need_hb) {
        egnn_setup<<<2048, 256, 0, stream>>>(h, pos, eidx, We1, We2, Wc1, Wn1, Wn2,
                                             out, ws, deg, 0, N);
        egnn_edge_mfma<1, 1, 0><<<ntiles, 512, 0, stream>>>(
            h, hb, pos, eidx, rc, We1F, We1r, be1, We2F, be2, Wc1F, bc1, Wc2,
            aggb, aggf, pos_out, E);
        egnn_node_mfma<1, 1><<<(N + 63) / 64, 512, 0, stream>>>(
            h, hb, aggb, aggf, Wn1F, bn1, Wn2F, bn2, out, N);
    } else if (ws_size >= need_ba) {
        egnn_prep<<<128, 256, 0, stream>>>(We1, We2, Wc1, Wn1, Wn2, ws);
        egnn_init_ba<<<2048, 256, 0, stream>>>(pos, out, (uint4*)aggb, N);
        egnn_edge_mfma<1, 0, 0><<<ntiles, 512, 0, stream>>>(
            h, hb, pos, eidx, rc, We1F, We1r, be1, We2F, be2, Wc1F, bc1, Wc2,
            aggb, aggf, pos_out, E);
        egnn_node_mfma<1, 0><<<(N + 63) / 64, 512, 0, stream>>>(
            h, hb, aggb, aggf, Wn1F, bn1, Wn2F, bn2, out, N);
    } else {
        egnn_prep<<<128, 256, 0, stream>>>(We1, We2, Wc1, Wn1, Wn2, ws);
        egnn_init_f32<<<2048, 256, 0, stream>>>(pos, out, N);
        egnn_edge_mfma<0, 0, 0><<<ntiles, 512, 0, stream>>>(
            h, hb, pos, eidx, rc, We1F, We1r, be1, We2F, be2, Wc1F, bc1, Wc2,
            aggb, aggf, pos_out, E);
        egnn_node_mfma<0, 0><<<(N + 63) / 64, 512, 0, stream>>>(
            h, hb, aggb, aggf, Wn1F, bn1, Wn2F, bn2, out, N);
    }
}